// Round 11
// baseline (1088.730 us; speedup 1.0000x reference)
//
#include <hip/hip_runtime.h>
#include <cstdint>
#include <cstddef>
#include <math.h>

#define NB   4096
#define NT   512
#define NRNN 25
#define NHID 20

typedef float v2f __attribute__((ext_vector_type(2)));

constexpr int GROUPS = 8;                 // 32-lane groups per block
constexpr int BLOCK  = 32 * GROUPS;       // 256 threads
constexpr int GRID   = NB / (GROUPS * 2); // 256 blocks: 2 batches per group (ILP)

constexpr size_t PREDX_N  = (size_t)NB * NT * 2;
constexpr size_t Z0_OFF   = PREDX_N;
constexpr size_t MEAN_OFF = Z0_OFF + (size_t)NB * 4;
constexpr size_t LV_OFF   = MEAN_OFF + (size_t)NB * 4;

__device__ __forceinline__ float bf2f(uint16_t u) {
    union { uint32_t i; float f; } c; c.i = ((uint32_t)u) << 16; return c.f;
}
__device__ __forceinline__ uint16_t f2bf(float f) {
    union { float ff; uint32_t i; } c; c.ff = f;
    return (uint16_t)((c.i + 0x7fffu + ((c.i >> 16) & 1u)) >> 16);  // RNE
}
__device__ __forceinline__ float ldin(const void* p, int i, bool bf) {
    return bf ? bf2f(((const uint16_t*)p)[i]) : ((const float*)p)[i];
}
__device__ __forceinline__ double ldind(const void* p, int i, bool bf) {
    return (double)ldin(p, i, bf);
}
__device__ __forceinline__ void wbar() {
    __asm__ volatile("" ::: "memory");
    __builtin_amdgcn_wave_barrier();
    __asm__ volatile("" ::: "memory");
}
__device__ __forceinline__ v2f pkfma(v2f a, v2f b, v2f c) {
#if __has_builtin(__builtin_elementwise_fma)
    return __builtin_elementwise_fma(a, b, c);
#else
    v2f r; r.x = __builtin_fmaf(a.x, b.x, c.x); r.y = __builtin_fmaf(a.y, b.y, c.y);
    return r;
#endif
}
// fast ELU tail via native v_exp_f32 (abs err ~3e-7; validated R10: absmax pinned)
__device__ __forceinline__ float fast_elu(float x) {
    return x > 0.f ? x : __expf(x) - 1.f;
}
template <int CTRL>
__device__ __forceinline__ float dpp_movf(float v) {
    return __int_as_float(__builtin_amdgcn_update_dpp(
        0, __float_as_int(v), CTRL, 0xf, 0xf, true));
}
__device__ __forceinline__ float swz16(float v) {
    return __int_as_float(__builtin_amdgcn_ds_swizzle(__float_as_int(v), 0x401F));
}

__global__ void __launch_bounds__(BLOCK)
node_kernel(const void* __restrict__ trajs,   // (B,T,2)
            const void* __restrict__ ts,      // (T)
            const void* __restrict__ eps,     // (B,4)
            const void* __restrict__ i2h_w, const void* __restrict__ i2h_b,
            const void* __restrict__ h2o_w, const void* __restrict__ h2o_b,
            const void* __restrict__ f1w, const void* __restrict__ f1b,
            const void* __restrict__ f2w, const void* __restrict__ f2b,
            const void* __restrict__ f3w, const void* __restrict__ f3b,
            const void* __restrict__ d1w, const void* __restrict__ d1b,
            const void* __restrict__ d2w, const void* __restrict__ d2b,
            void* __restrict__ out)
{
    // dtype probe: samp_ts[0]=0.0, samp_ts[1]=0.01.
    const bool bf = (((const uint32_t*)ts)[0] != 0u);

    __shared__ __align__(16) float s_x[GROUPS][2][NT * 2];  // 64 KB, RO after sync
    __shared__ float s_dt[NT];
    __shared__ __align__(16) float s_g[GROUPS][64];         // gather buf: A|B halves

    const int tid  = threadIdx.x;
    const int grp  = tid >> 5;
    const int lane = tid & 31;
    const int b0   = (blockIdx.x * GROUPS + grp) * 2;       // batches b0, b0+1
    float* sg = &s_g[grp][0];
    const bool lo1 = (lane & 1) != 0;
    const bool lo2 = (lane & 2) != 0;

    for (int i = tid; i < NT - 1; i += BLOCK)
        s_dt[i] = ldin(ts, i + 1, bf) - ldin(ts, i, bf);

    #pragma unroll
    for (int q = 0; q < 2; ++q) {
        if (bf) {
            const uint32_t* tr32 = (const uint32_t*)trajs + (size_t)(b0 + q) * NT;
            #pragma unroll 4
            for (int k = 0; k < NT / 32; ++k) {
                uint32_t v = tr32[lane + 32 * k];
                *(float2*)&s_x[grp][q][(size_t)(lane + 32 * k) * 2] =
                    make_float2(bf2f((uint16_t)(v & 0xffffu)), bf2f((uint16_t)(v >> 16)));
            }
        } else {
            const float2* trf = (const float2*)trajs + (size_t)(b0 + q) * NT;
            #pragma unroll 4
            for (int k = 0; k < NT / 32; ++k)
                *(float2*)&s_x[grp][q][(size_t)(lane + 32 * k) * 2] = trf[lane + 32 * k];
        }
    }
    sg[lane] = 0.f;
    sg[32 + lane] = 0.f;
    __syncthreads();

    // ---------------- Phase 1: reverse RNN, 2 batches interleaved ----------------
    float whs[28];
    #pragma unroll
    for (int i = 0; i < 28; ++i) whs[i] = 0.f;
    float wx0 = 0.f, wx1 = 0.f, wb = 0.f;
    if (lane < NRNN) {
        wx0 = ldin(i2h_w, lane, bf);
        wx1 = ldin(i2h_w, NRNN + lane, bf);
        #pragma unroll
        for (int i = 0; i < NRNN; ++i) whs[i] = ldin(i2h_w, (2 + i) * NRNN + lane, bf);
        wb = ldin(i2h_b, lane, bf);
    }
    v2f wxp = {wx0, wx1};
    v2f whp[14];
    #pragma unroll
    for (int m = 0; m < 14; ++m) { whp[m].x = whs[2 * m]; whp[m].y = whs[2 * m + 1]; }

    auto rnn_pre = [&](const float4* g4, float2 x) -> float {
        float4 v0 = g4[0], v1 = g4[1], v2 = g4[2], v3 = g4[3];
        float4 v4 = g4[4], v5 = g4[5], v6 = g4[6];
        v2f xv = {x.x, x.y};
        v2f p0 = {v0.x, v0.y}, p1 = {v0.z, v0.w}, p2 = {v1.x, v1.y}, p3 = {v1.z, v1.w};
        v2f p4 = {v2.x, v2.y}, p5 = {v2.z, v2.w}, p6 = {v3.x, v3.y}, p7 = {v3.z, v3.w};
        v2f p8 = {v4.x, v4.y}, p9 = {v4.z, v4.w}, pA = {v5.x, v5.y}, pB = {v5.z, v5.w};
        v2f pC = {v6.x, v6.y}, pD = {v6.z, v6.w};
        v2f A = xv * wxp;
        A = pkfma(p1, whp[1], A); A = pkfma(p3, whp[3], A); A = pkfma(p5, whp[5], A);
        A = pkfma(p7, whp[7], A); A = pkfma(p9, whp[9], A); A = pkfma(pB, whp[11], A);
        A = pkfma(pD, whp[13], A);
        v2f B = p0 * whp[0];
        B = pkfma(p2, whp[2], B); B = pkfma(p4, whp[4], B); B = pkfma(p6, whp[6], B);
        B = pkfma(p8, whp[8], B); B = pkfma(pA, whp[10], B); B = pkfma(pC, whp[12], B);
        return ((A.x + B.x) + (A.y + B.y)) + wb;
    };

    float hA = 0.f, hB = 0.f;
    for (int t = NT - 1; t >= 0; --t) {
        sg[lane] = hA;                   // lanes>=25 keep 0
        sg[32 + lane] = hB;
        wbar();
        float preA = rnn_pre((const float4*)sg,        *(const float2*)&s_x[grp][0][2 * t]);
        float preB = rnn_pre((const float4*)(sg + 32), *(const float2*)&s_x[grp][1][2 * t]);
        wbar();
        hA = tanhf(preA);                // ocml tanh kept (accuracy anchor)
        hB = tanhf(preB);
    }

    // ---------------- Phase 2: h2o + reparameterize (one-time, per batch) ----------------
    double zdA[4], zdB[4];
    auto phase2 = [&](float h, int b, double* zd) {
        double hl[NRNN];
        #pragma unroll
        for (int j = 0; j < NRNN; ++j) hl[j] = (double)__shfl(h, j, 32);
        double o = 0.0;
        if (lane < 8) {
            double a0 = 0, a1 = 0, a2 = 0, a3 = 0;
            #pragma unroll
            for (int i = 0; i < 24; i += 4) {
                a0 += hl[i + 0] * ldind(h2o_w, (i + 0) * 8 + lane, bf);
                a1 += hl[i + 1] * ldind(h2o_w, (i + 1) * 8 + lane, bf);
                a2 += hl[i + 2] * ldind(h2o_w, (i + 2) * 8 + lane, bf);
                a3 += hl[i + 3] * ldind(h2o_w, (i + 3) * 8 + lane, bf);
            }
            a0 += hl[24] * ldind(h2o_w, 24 * 8 + lane, bf);
            o = ((a0 + a1) + (a2 + a3)) + ldind(h2o_b, lane, bf);
        }
        double mean[4], lv[4];
        #pragma unroll
        for (int c = 0; c < 4; ++c) {
            mean[c] = __shfl(o, c, 32);
            lv[c]   = __shfl(o, 4 + c, 32);
        }
        double ep[4];
        if (bf) {
            const uint32_t* e32 = (const uint32_t*)eps + (size_t)b * 2;
            uint32_t e0 = e32[0], e1 = e32[1];
            ep[0] = bf2f((uint16_t)(e0 & 0xffffu)); ep[1] = bf2f((uint16_t)(e0 >> 16));
            ep[2] = bf2f((uint16_t)(e1 & 0xffffu)); ep[3] = bf2f((uint16_t)(e1 >> 16));
        } else {
            const float* ef = (const float*)eps + (size_t)b * 4;
            #pragma unroll
            for (int c = 0; c < 4; ++c) ep[c] = ef[c];
        }
        #pragma unroll
        for (int c = 0; c < 4; ++c)
            zd[c] = ep[c] * exp(0.5 * lv[c]) + mean[c];
        if (lane < 4) {
            double zv  = lane == 0 ? zd[0] : lane == 1 ? zd[1] : lane == 2 ? zd[2] : zd[3];
            double mv  = lane == 0 ? mean[0] : lane == 1 ? mean[1] : lane == 2 ? mean[2] : mean[3];
            double lvv = lane == 0 ? lv[0] : lane == 1 ? lv[1] : lane == 2 ? lv[2] : lv[3];
            if (bf) {
                uint16_t* o16 = (uint16_t*)out;
                o16[Z0_OFF   + (size_t)b * 4 + lane] = f2bf((float)zv);
                o16[MEAN_OFF + (size_t)b * 4 + lane] = f2bf((float)mv);
                o16[LV_OFF   + (size_t)b * 4 + lane] = f2bf((float)lvv);
            } else {
                float* of = (float*)out;
                of[Z0_OFF   + (size_t)b * 4 + lane] = (float)zv;
                of[MEAN_OFF + (size_t)b * 4 + lane] = (float)mv;
                of[LV_OFF   + (size_t)b * 4 + lane] = (float)lvv;
            }
        }
    };
    phase2(hA, b0, zdA);
    phase2(hB, b0 + 1, zdB);

    // ---------------- Phase 3: RK4 ODE, 2 batches interleaved ----------------
    float f2s[NHID], f3r[4] = {0,0,0,0};
    float f1bb = 0.f, f2bb = 0.f, d1bb = 0.f, d2r0 = 0.f, d2r1 = 0.f;
    v2f f1p0 = {0,0}, f1p1 = {0,0}, d1p0 = {0,0}, d1p1 = {0,0};
    #pragma unroll
    for (int i = 0; i < NHID; ++i) f2s[i] = 0.f;
    if (lane < NHID) {
        f1p0.x = ldin(f1w, 0 * NHID + lane, bf);
        f1p0.y = ldin(f1w, 1 * NHID + lane, bf);
        f1p1.x = ldin(f1w, 2 * NHID + lane, bf);
        f1p1.y = ldin(f1w, 3 * NHID + lane, bf);
        f1bb = ldin(f1b, lane, bf);
        #pragma unroll
        for (int i = 0; i < NHID; ++i) f2s[i] = ldin(f2w, i * NHID + lane, bf);
        f2bb = ldin(f2b, lane, bf);
        #pragma unroll
        for (int c = 0; c < 4; ++c) f3r[c] = ldin(f3w, lane * 4 + c, bf);
        d1p0.x = ldin(d1w, 0 * NHID + lane, bf);
        d1p0.y = ldin(d1w, 1 * NHID + lane, bf);
        d1p1.x = ldin(d1w, 2 * NHID + lane, bf);
        d1p1.y = ldin(d1w, 3 * NHID + lane, bf);
        d1bb = ldin(d1b, lane, bf);
        d2r0 = ldin(d2w, lane * 2 + 0, bf);
        d2r1 = ldin(d2w, lane * 2 + 1, bf);
    }
    v2f f2p[10];
    #pragma unroll
    for (int m = 0; m < 10; ++m) { f2p[m].x = f2s[2 * m]; f2p[m].y = f2s[2 * m + 1]; }
    float f3bc[4];
    #pragma unroll
    for (int c = 0; c < 4; ++c) f3bc[c] = ldin(f3b, c, bf);
    const float f3bl = lo2 ? (lo1 ? f3bc[3] : f3bc[2]) : (lo1 ? f3bc[1] : f3bc[0]);
    const float d2b0 = ldin(d2b, 0, bf), d2b1 = ldin(d2b, 1, bf);
    const float d2bl = lo1 ? d2b1 : d2b0;

    auto f2dot = [&](const float4* g4) -> float {
        float4 v0 = g4[0], v1 = g4[1], v2 = g4[2], v3 = g4[3], v4 = g4[4];
        v2f q0 = {v0.x, v0.y}, q1 = {v0.z, v0.w}, q2 = {v1.x, v1.y}, q3 = {v1.z, v1.w};
        v2f q4 = {v2.x, v2.y}, q5 = {v2.z, v2.w}, q6 = {v3.x, v3.y}, q7 = {v3.z, v3.w};
        v2f q8 = {v4.x, v4.y}, q9 = {v4.z, v4.w};
        v2f A = q0 * f2p[0];
        A = pkfma(q2, f2p[2], A); A = pkfma(q4, f2p[4], A);
        A = pkfma(q6, f2p[6], A); A = pkfma(q8, f2p[8], A);
        v2f B = q1 * f2p[1];
        B = pkfma(q3, f2p[3], B); B = pkfma(q5, f2p[5], B);
        B = pkfma(q7, f2p[7], B); B = pkfma(q9, f2p[9], B);
        return ((A.x + B.x) + (A.y + B.y)) + f2bb;
    };
    auto redk = [&](float u2, v2f& k01, v2f& k23) {
        float q0s = u2 * f3r[0], q1s = u2 * f3r[1], q2s = u2 * f3r[2], q3s = u2 * f3r[3];
        float x0 = q0s + dpp_movf<0xB1>(q0s);
        float x1 = q1s + dpp_movf<0xB1>(q1s);
        float x2 = q2s + dpp_movf<0xB1>(q2s);
        float x3 = q3s + dpp_movf<0xB1>(q3s);
        float a  = lo1 ? x1 : x0;
        float c  = lo1 ? x3 : x2;
        a += dpp_movf<0x4E>(a);
        c += dpp_movf<0x4E>(c);
        float v = lo2 ? c : a;
        v += dpp_movf<0x124>(v);
        v += dpp_movf<0x128>(v);
        v += swz16(v);
        v += f3bl;
        k01.x = dpp_movf<0x00>(v);
        k01.y = dpp_movf<0x55>(v);
        k23.x = dpp_movf<0xAA>(v);
        k23.y = dpp_movf<0xFF>(v);
    };

    auto feval2 = [&](v2f zA01, v2f zA23, v2f zB01, v2f zB23,
                      v2f& kA01, v2f& kA23, v2f& kB01, v2f& kB23) {
        v2f tdA = pkfma(zA23, f1p1, zA01 * f1p0);
        v2f tdB = pkfma(zB23, f1p1, zB01 * f1p0);
        float u1A = fast_elu((tdA.x + tdA.y) + f1bb);
        float u1B = fast_elu((tdB.x + tdB.y) + f1bb);
        sg[lane] = u1A;
        sg[32 + lane] = u1B;
        wbar();
        float u2A = f2dot((const float4*)sg);
        float u2B = f2dot((const float4*)(sg + 32));
        wbar();
        u2A = fast_elu(u2A);
        u2B = fast_elu(u2B);
        redk(u2A, kA01, kA23);
        redk(u2B, kB01, kB23);
    };

    auto dec1 = [&](v2f zi01, v2f zi23) -> float2 {
        v2f td = pkfma(zi23, d1p1, zi01 * d1p0);
        float r = (td.x + td.y) + d1bb;
        r = fmaxf(r, 0.f);
        float p0 = r * d2r0, p1 = r * d2r1;
        float x0 = p0 + dpp_movf<0xB1>(p0);
        float x1 = p1 + dpp_movf<0xB1>(p1);
        float a  = lo1 ? x1 : x0;
        a += dpp_movf<0x4E>(a);
        a += dpp_movf<0x124>(a);
        a += dpp_movf<0x128>(a);
        a += swz16(a);
        a += d2bl;
        float a1v = dpp_movf<0x55>(a);
        return make_float2(a, a1v);
    };
    auto decode2 = [&](v2f zA01, v2f zA23, v2f zB01, v2f zB23, int t) {
        float2 rA = dec1(zA01, zA23);
        float2 rB = dec1(zB01, zB23);
        if (lane == 0) {
            if (bf) {
                uint32_t wA = (uint32_t)f2bf(rA.x) | ((uint32_t)f2bf(rA.y) << 16);
                uint32_t wB = (uint32_t)f2bf(rB.x) | ((uint32_t)f2bf(rB.y) << 16);
                *(uint32_t*)((uint16_t*)out + ((size_t)b0 * NT + t) * 2) = wA;
                *(uint32_t*)((uint16_t*)out + ((size_t)(b0 + 1) * NT + t) * 2) = wB;
            } else {
                ((float2*)out)[(size_t)b0 * NT + t] = rA;
                ((float2*)out)[(size_t)(b0 + 1) * NT + t] = rB;
            }
        }
    };

    v2f zA01, zA23, zB01, zB23;
    zA01.x = (float)zdA[0]; zA01.y = (float)zdA[1];
    zA23.x = (float)zdA[2]; zA23.y = (float)zdA[3];
    zB01.x = (float)zdB[0]; zB01.y = (float)zdB[1];
    zB23.x = (float)zdB[2]; zB23.y = (float)zdB[3];
    decode2(zA01, zA23, zB01, zB23, 0);
    for (int s = 0; s < NT - 1; ++s) {
        float dt = s_dt[s];
        v2f k1aA, k1bA, k2aA, k2bA, k3aA, k3bA, k4aA, k4bA;
        v2f k1aB, k1bB, k2aB, k2bB, k3aB, k3bB, k4aB, k4bB;
        feval2(zA01, zA23, zB01, zB23, k1aA, k1bA, k1aB, k1bB);
        float hdt = 0.5f * dt;
        v2f hv = {hdt, hdt};
        v2f tA01 = pkfma(hv, k1aA, zA01), tA23 = pkfma(hv, k1bA, zA23);
        v2f tB01 = pkfma(hv, k1aB, zB01), tB23 = pkfma(hv, k1bB, zB23);
        feval2(tA01, tA23, tB01, tB23, k2aA, k2bA, k2aB, k2bB);
        tA01 = pkfma(hv, k2aA, zA01); tA23 = pkfma(hv, k2bA, zA23);
        tB01 = pkfma(hv, k2aB, zB01); tB23 = pkfma(hv, k2bB, zB23);
        feval2(tA01, tA23, tB01, tB23, k3aA, k3bA, k3aB, k3bB);
        v2f dv = {dt, dt};
        tA01 = pkfma(dv, k3aA, zA01); tA23 = pkfma(dv, k3bA, zA23);
        tB01 = pkfma(dv, k3aB, zB01); tB23 = pkfma(dv, k3bB, zB23);
        feval2(tA01, tA23, tB01, tB23, k4aA, k4bA, k4aB, k4bB);
        float dt6 = dt * (1.f / 6.f);
        v2f d6 = {dt6, dt6};
        v2f mA01 = k2aA + k3aA, mA23 = k2bA + k3bA;
        v2f mB01 = k2aB + k3aB, mB23 = k2bB + k3bB;
        v2f sA01 = (k1aA + (mA01 + mA01)) + k4aA;
        v2f sA23 = (k1bA + (mA23 + mA23)) + k4bA;
        v2f sB01 = (k1aB + (mB01 + mB01)) + k4aB;
        v2f sB23 = (k1bB + (mB23 + mB23)) + k4bB;
        v2f iA01 = d6 * sA01, iA23 = d6 * sA23;
        v2f iB01 = d6 * sB01, iB23 = d6 * sB23;
        // f64 state accumulate from f32 increments (anchor: f64 state chain)
        zdA[0] += (double)iA01.x; zdA[1] += (double)iA01.y;
        zdA[2] += (double)iA23.x; zdA[3] += (double)iA23.y;
        zdB[0] += (double)iB01.x; zdB[1] += (double)iB01.y;
        zdB[2] += (double)iB23.x; zdB[3] += (double)iB23.y;
        zA01.x = (float)zdA[0]; zA01.y = (float)zdA[1];
        zA23.x = (float)zdA[2]; zA23.y = (float)zdA[3];
        zB01.x = (float)zdB[0]; zB01.y = (float)zdB[1];
        zB23.x = (float)zdB[2]; zB23.y = (float)zdB[3];
        decode2(zA01, zA23, zB01, zB23, s + 1);
    }
}

extern "C" void kernel_launch(void* const* d_in, const int* in_sizes, int n_in,
                              void* d_out, int out_size, void* d_ws, size_t ws_size,
                              hipStream_t stream) {
    (void)in_sizes; (void)n_in; (void)out_size; (void)d_ws; (void)ws_size;
    node_kernel<<<GRID, BLOCK, 0, stream>>>(
        d_in[0],  // samp_trajs
        d_in[1],  // samp_ts
        d_in[2],  // epsilon
        d_in[3],  d_in[4],   // i2h
        d_in[5],  d_in[6],   // h2o
        d_in[7],  d_in[8],   // f1
        d_in[9],  d_in[10],  // f2
        d_in[11], d_in[12],  // f3
        d_in[13], d_in[14],  // d1
        d_in[15], d_in[16],  // d2
        d_out);
}

// Round 12
// 785.456 us; speedup vs baseline: 1.3861x; 1.3861x over previous
//
#include <hip/hip_runtime.h>
#include <cstdint>
#include <cstddef>
#include <math.h>

#define NB   4096
#define NT   512
#define NRNN 25
#define NHID 20

typedef float v2f __attribute__((ext_vector_type(2)));

constexpr int GROUPS = 8;            // batches per block (one per 32-lane group)
constexpr int BLOCK  = 32 * GROUPS;  // 256 threads
constexpr int GRID   = NB / GROUPS;  // 512 blocks -> 2048 waves, 2/SIMD (R10 anchor)

constexpr size_t PREDX_N  = (size_t)NB * NT * 2;
constexpr size_t Z0_OFF   = PREDX_N;
constexpr size_t MEAN_OFF = Z0_OFF + (size_t)NB * 4;
constexpr size_t LV_OFF   = MEAN_OFF + (size_t)NB * 4;

__device__ __forceinline__ float bf2f(uint16_t u) {
    union { uint32_t i; float f; } c; c.i = ((uint32_t)u) << 16; return c.f;
}
__device__ __forceinline__ uint16_t f2bf(float f) {
    union { float ff; uint32_t i; } c; c.ff = f;
    return (uint16_t)((c.i + 0x7fffu + ((c.i >> 16) & 1u)) >> 16);  // RNE
}
__device__ __forceinline__ float ldin(const void* p, int i, bool bf) {
    return bf ? bf2f(((const uint16_t*)p)[i]) : ((const float*)p)[i];
}
__device__ __forceinline__ double ldind(const void* p, int i, bool bf) {
    return (double)ldin(p, i, bf);
}
__device__ __forceinline__ void wbar() {
    __asm__ volatile("" ::: "memory");
    __builtin_amdgcn_wave_barrier();
    __asm__ volatile("" ::: "memory");
}
__device__ __forceinline__ v2f pkfma(v2f a, v2f b, v2f c) {
#if __has_builtin(__builtin_elementwise_fma)
    return __builtin_elementwise_fma(a, b, c);
#else
    v2f r; r.x = __builtin_fmaf(a.x, b.x, c.x); r.y = __builtin_fmaf(a.y, b.y, c.y);
    return r;
#endif
}
// fast ELU tail via native v_exp_f32 (validated R10)
__device__ __forceinline__ float fast_elu(float x) {
    return x > 0.f ? x : __expf(x) - 1.f;
}
// fast tanh: 1 - 2/(e^{2x}+1); ~5 inst, abs err ~1e-6, graceful at +-inf
__device__ __forceinline__ float fast_tanh(float x) {
    float e = __expf(2.f * x);
    return 1.f - 2.f * __builtin_amdgcn_rcpf(e + 1.f);
}
template <int CTRL>
__device__ __forceinline__ float dpp_movf(float v) {
    return __int_as_float(__builtin_amdgcn_update_dpp(
        0, __float_as_int(v), CTRL, 0xf, 0xf, true));
}
__device__ __forceinline__ float swz16(float v) {
    return __int_as_float(__builtin_amdgcn_ds_swizzle(__float_as_int(v), 0x401F));
}

__global__ void __launch_bounds__(BLOCK)
node_kernel(const void* __restrict__ trajs,   // (B,T,2)
            const void* __restrict__ ts,      // (T)
            const void* __restrict__ eps,     // (B,4)
            const void* __restrict__ i2h_w, const void* __restrict__ i2h_b,
            const void* __restrict__ h2o_w, const void* __restrict__ h2o_b,
            const void* __restrict__ f1w, const void* __restrict__ f1b,
            const void* __restrict__ f2w, const void* __restrict__ f2b,
            const void* __restrict__ f3w, const void* __restrict__ f3b,
            const void* __restrict__ d1w, const void* __restrict__ d1b,
            const void* __restrict__ d2w, const void* __restrict__ d2b,
            void* __restrict__ out)
{
    // dtype probe: samp_ts[0]=0.0, samp_ts[1]=0.01.
    const bool bf = (((const uint32_t*)ts)[0] != 0u);

    __shared__ __align__(16) float s_x[GROUPS][NT * 2];  // read-only after sync
    __shared__ float s_dt[NT];
    __shared__ __align__(16) float s_g[GROUPS][32];      // per-group gather buf

    const int tid  = threadIdx.x;
    const int grp  = tid >> 5;
    const int lane = tid & 31;
    const int b    = blockIdx.x * GROUPS + grp;
    float* sg = &s_g[grp][0];
    const bool lo1 = (lane & 1) != 0;
    const bool lo2 = (lane & 2) != 0;

    for (int i = tid; i < NT - 1; i += BLOCK)
        s_dt[i] = ldin(ts, i + 1, bf) - ldin(ts, i, bf);

    if (bf) {
        const uint32_t* tr32 = (const uint32_t*)trajs + (size_t)b * NT;
        #pragma unroll 4
        for (int k = 0; k < NT / 32; ++k) {
            uint32_t v = tr32[lane + 32 * k];
            *(float2*)&s_x[grp][(size_t)(lane + 32 * k) * 2] =
                make_float2(bf2f((uint16_t)(v & 0xffffu)), bf2f((uint16_t)(v >> 16)));
        }
    } else {
        const float2* trf = (const float2*)trajs + (size_t)b * NT;
        #pragma unroll 4
        for (int k = 0; k < NT / 32; ++k)
            *(float2*)&s_x[grp][(size_t)(lane + 32 * k) * 2] = trf[lane + 32 * k];
    }
    sg[lane] = 0.f;
    __syncthreads();

    // ---------------- Phase 1: reverse RNN (f32, packed dots, fast tanh) ----------------
    float whs[28];
    #pragma unroll
    for (int i = 0; i < 28; ++i) whs[i] = 0.f;
    float wx0 = 0.f, wx1 = 0.f, wb = 0.f;
    if (lane < NRNN) {
        wx0 = ldin(i2h_w, lane, bf);
        wx1 = ldin(i2h_w, NRNN + lane, bf);
        #pragma unroll
        for (int i = 0; i < NRNN; ++i) whs[i] = ldin(i2h_w, (2 + i) * NRNN + lane, bf);
        wb = ldin(i2h_b, lane, bf);
    }
    v2f wxp = {wx0, wx1};
    v2f whp[14];
    #pragma unroll
    for (int m = 0; m < 14; ++m) { whp[m].x = whs[2 * m]; whp[m].y = whs[2 * m + 1]; }

    float h = 0.f;
    for (int t = NT - 1; t >= 0; --t) {
        // x-load first: its LDS latency overlaps the h-gather round trip
        float2 x = *(const float2*)&s_x[grp][2 * t];
        sg[lane] = h;                    // lanes>=25 keep h=0
        v2f xv = {x.x, x.y};
        v2f A = xv * wxp;                // independent work in the write->read window
        wbar();
        const float4* g4 = (const float4*)sg;
        float4 v0 = g4[0], v1 = g4[1], v2 = g4[2], v3 = g4[3];
        float4 v4 = g4[4], v5 = g4[5], v6 = g4[6];
        wbar();
        v2f p0 = {v0.x, v0.y}, p1 = {v0.z, v0.w}, p2 = {v1.x, v1.y}, p3 = {v1.z, v1.w};
        v2f p4 = {v2.x, v2.y}, p5 = {v2.z, v2.w}, p6 = {v3.x, v3.y}, p7 = {v3.z, v3.w};
        v2f p8 = {v4.x, v4.y}, p9 = {v4.z, v4.w}, pA = {v5.x, v5.y}, pB = {v5.z, v5.w};
        v2f pC = {v6.x, v6.y}, pD = {v6.z, v6.w};
        A = pkfma(p1, whp[1], A); A = pkfma(p3, whp[3], A); A = pkfma(p5, whp[5], A);
        A = pkfma(p7, whp[7], A); A = pkfma(p9, whp[9], A); A = pkfma(pB, whp[11], A);
        A = pkfma(pD, whp[13], A);
        v2f B = p0 * whp[0];
        B = pkfma(p2, whp[2], B); B = pkfma(p4, whp[4], B); B = pkfma(p6, whp[6], B);
        B = pkfma(p8, whp[8], B); B = pkfma(pA, whp[10], B); B = pkfma(pC, whp[12], B);
        h = fast_tanh(((A.x + B.x) + (A.y + B.y)) + wb);
    }

    // ---------------- Phase 2: h2o + reparameterize (f64, one-time) ----------------
    double hl[NRNN];
    #pragma unroll
    for (int j = 0; j < NRNN; ++j) hl[j] = (double)__shfl(h, j, 32);

    double o = 0.0;
    if (lane < 8) {
        double a0 = 0, a1 = 0, a2 = 0, a3 = 0;
        #pragma unroll
        for (int i = 0; i < 24; i += 4) {
            a0 += hl[i + 0] * ldind(h2o_w, (i + 0) * 8 + lane, bf);
            a1 += hl[i + 1] * ldind(h2o_w, (i + 1) * 8 + lane, bf);
            a2 += hl[i + 2] * ldind(h2o_w, (i + 2) * 8 + lane, bf);
            a3 += hl[i + 3] * ldind(h2o_w, (i + 3) * 8 + lane, bf);
        }
        a0 += hl[24] * ldind(h2o_w, 24 * 8 + lane, bf);
        o = ((a0 + a1) + (a2 + a3)) + ldind(h2o_b, lane, bf);
    }
    double mean[4], lv[4];
    #pragma unroll
    for (int c = 0; c < 4; ++c) {
        mean[c] = __shfl(o, c, 32);
        lv[c]   = __shfl(o, 4 + c, 32);
    }
    double ep[4];
    if (bf) {
        const uint32_t* e32 = (const uint32_t*)eps + (size_t)b * 2;
        uint32_t e0 = e32[0], e1 = e32[1];
        ep[0] = bf2f((uint16_t)(e0 & 0xffffu)); ep[1] = bf2f((uint16_t)(e0 >> 16));
        ep[2] = bf2f((uint16_t)(e1 & 0xffffu)); ep[3] = bf2f((uint16_t)(e1 >> 16));
    } else {
        const float* ef = (const float*)eps + (size_t)b * 4;
        #pragma unroll
        for (int c = 0; c < 4; ++c) ep[c] = ef[c];
    }
    double zd[4];
    #pragma unroll
    for (int c = 0; c < 4; ++c)
        zd[c] = ep[c] * exp(0.5 * lv[c]) + mean[c];

    if (lane < 4) {
        double zv  = lane == 0 ? zd[0] : lane == 1 ? zd[1] : lane == 2 ? zd[2] : zd[3];
        double mv  = lane == 0 ? mean[0] : lane == 1 ? mean[1] : lane == 2 ? mean[2] : mean[3];
        double lvv = lane == 0 ? lv[0] : lane == 1 ? lv[1] : lane == 2 ? lv[2] : lv[3];
        if (bf) {
            uint16_t* o16 = (uint16_t*)out;
            o16[Z0_OFF   + (size_t)b * 4 + lane] = f2bf((float)zv);
            o16[MEAN_OFF + (size_t)b * 4 + lane] = f2bf((float)mv);
            o16[LV_OFF   + (size_t)b * 4 + lane] = f2bf((float)lvv);
        } else {
            float* of = (float*)out;
            of[Z0_OFF   + (size_t)b * 4 + lane] = (float)zv;
            of[MEAN_OFF + (size_t)b * 4 + lane] = (float)mv;
            of[LV_OFF   + (size_t)b * 4 + lane] = (float)lvv;
        }
    }

    // ---------------- Phase 3: RK4 ODE (f64 state, pipelined f32 feval) ----------------
    float f2s[NHID], f3r[4] = {0,0,0,0};
    float f1bb = 0.f, f2bb = 0.f, d1bb = 0.f, d2r0 = 0.f, d2r1 = 0.f;
    v2f f1p0 = {0,0}, f1p1 = {0,0}, d1p0 = {0,0}, d1p1 = {0,0};
    #pragma unroll
    for (int i = 0; i < NHID; ++i) f2s[i] = 0.f;
    if (lane < NHID) {
        f1p0.x = ldin(f1w, 0 * NHID + lane, bf);
        f1p0.y = ldin(f1w, 1 * NHID + lane, bf);
        f1p1.x = ldin(f1w, 2 * NHID + lane, bf);
        f1p1.y = ldin(f1w, 3 * NHID + lane, bf);
        f1bb = ldin(f1b, lane, bf);
        #pragma unroll
        for (int i = 0; i < NHID; ++i) f2s[i] = ldin(f2w, i * NHID + lane, bf);
        f2bb = ldin(f2b, lane, bf);
        #pragma unroll
        for (int c = 0; c < 4; ++c) f3r[c] = ldin(f3w, lane * 4 + c, bf);
        d1p0.x = ldin(d1w, 0 * NHID + lane, bf);
        d1p0.y = ldin(d1w, 1 * NHID + lane, bf);
        d1p1.x = ldin(d1w, 2 * NHID + lane, bf);
        d1p1.y = ldin(d1w, 3 * NHID + lane, bf);
        d1bb = ldin(d1b, lane, bf);
        d2r0 = ldin(d2w, lane * 2 + 0, bf);
        d2r1 = ldin(d2w, lane * 2 + 1, bf);
    }
    v2f f2p[10];
    #pragma unroll
    for (int m = 0; m < 10; ++m) { f2p[m].x = f2s[2 * m]; f2p[m].y = f2s[2 * m + 1]; }
    float f3bc[4];
    #pragma unroll
    for (int c = 0; c < 4; ++c) f3bc[c] = ldin(f3b, c, bf);
    const float f3bl = lo2 ? (lo1 ? f3bc[3] : f3bc[2]) : (lo1 ? f3bc[1] : f3bc[0]);
    const float d2b0 = ldin(d2b, 0, bf), d2b1 = ldin(d2b, 1, bf);
    const float d2bl = lo1 ? d2b1 : d2b0;

    // feval split: pre = f1 dot + elu + ds_write; post = gather + f2 + reduce.
    // Independent code placed between pre and post fills the LDS round-trip window.
    auto feval_pre = [&](v2f zi01, v2f zi23) {
        v2f td = pkfma(zi23, f1p1, zi01 * f1p0);
        float u1 = fast_elu((td.x + td.y) + f1bb);   // lanes>=20 -> 0
        sg[lane] = u1;
    };
    auto feval_post = [&](v2f& k01, v2f& k23) {
        wbar();
        const float4* g4 = (const float4*)sg;
        float4 v0 = g4[0], v1 = g4[1], v2 = g4[2], v3 = g4[3], v4 = g4[4];
        wbar();
        v2f q0 = {v0.x, v0.y}, q1 = {v0.z, v0.w}, q2 = {v1.x, v1.y}, q3 = {v1.z, v1.w};
        v2f q4 = {v2.x, v2.y}, q5 = {v2.z, v2.w}, q6 = {v3.x, v3.y}, q7 = {v3.z, v3.w};
        v2f q8 = {v4.x, v4.y}, q9 = {v4.z, v4.w};
        v2f A = q0 * f2p[0];
        A = pkfma(q2, f2p[2], A); A = pkfma(q4, f2p[4], A);
        A = pkfma(q6, f2p[6], A); A = pkfma(q8, f2p[8], A);
        v2f B = q1 * f2p[1];
        B = pkfma(q3, f2p[3], B); B = pkfma(q5, f2p[5], B);
        B = pkfma(q7, f2p[7], B); B = pkfma(q9, f2p[9], B);
        float u2 = fast_elu(((A.x + B.x) + (A.y + B.y)) + f2bb);
        // fused 4-way allreduce: quad-transpose (DPP) + row_ror + xor16 swizzle
        float q0s = u2 * f3r[0], q1s = u2 * f3r[1], q2s = u2 * f3r[2], q3s = u2 * f3r[3];
        float x0 = q0s + dpp_movf<0xB1>(q0s);
        float x1 = q1s + dpp_movf<0xB1>(q1s);
        float x2 = q2s + dpp_movf<0xB1>(q2s);
        float x3 = q3s + dpp_movf<0xB1>(q3s);
        float a  = lo1 ? x1 : x0;
        float c  = lo1 ? x3 : x2;
        a += dpp_movf<0x4E>(a);
        c += dpp_movf<0x4E>(c);
        float v = lo2 ? c : a;
        v += dpp_movf<0x124>(v);
        v += dpp_movf<0x128>(v);
        v += swz16(v);
        v += f3bl;
        k01.x = dpp_movf<0x00>(v);
        k01.y = dpp_movf<0x55>(v);
        k23.x = dpp_movf<0xAA>(v);
        k23.y = dpp_movf<0xFF>(v);
    };

    auto decode = [&](v2f zi01, v2f zi23, int t) {
        v2f td = pkfma(zi23, d1p1, zi01 * d1p0);
        float r = (td.x + td.y) + d1bb;
        r = fmaxf(r, 0.f);                       // relu; lanes>=20 give 0
        float p0 = r * d2r0, p1 = r * d2r1;
        float x0 = p0 + dpp_movf<0xB1>(p0);
        float x1 = p1 + dpp_movf<0xB1>(p1);
        float a  = lo1 ? x1 : x0;
        a += dpp_movf<0x4E>(a);
        a += dpp_movf<0x124>(a);
        a += dpp_movf<0x128>(a);
        a += swz16(a);
        a += d2bl;
        float a1v = dpp_movf<0x55>(a);
        if (lane == 0) {
            if (bf) {
                uint32_t wv = (uint32_t)f2bf(a) | ((uint32_t)f2bf(a1v) << 16);
                *(uint32_t*)((uint16_t*)out + ((size_t)b * NT + t) * 2) = wv;
            } else {
                ((float2*)out)[(size_t)b * NT + t] = make_float2(a, a1v);
            }
        }
    };

    v2f z01, z23;
    z01.x = (float)zd[0]; z01.y = (float)zd[1];
    z23.x = (float)zd[2]; z23.y = (float)zd[3];
    for (int s = 0; s < NT - 1; ++s) {
        float dt = s_dt[s];
        v2f k1a, k1b, k2a, k2b, k3a, k3b, k4a, k4b;
        feval_pre(z01, z23);         // k1 write
        decode(z01, z23, s);         // fills the k1 LDS round-trip window
        feval_post(k1a, k1b);
        float hdt = 0.5f * dt;
        v2f hv = {hdt, hdt};
        v2f t01 = pkfma(hv, k1a, z01), t23 = pkfma(hv, k1b, z23);
        feval_pre(t01, t23);
        float dt6 = dt * (1.f / 6.f);  // small filler for k2 window
        v2f d6 = {dt6, dt6};
        v2f dv = {dt, dt};
        feval_post(k2a, k2b);
        t01 = pkfma(hv, k2a, z01); t23 = pkfma(hv, k2b, z23);
        feval_pre(t01, t23);
        feval_post(k3a, k3b);
        t01 = pkfma(dv, k3a, z01); t23 = pkfma(dv, k3b, z23);
        feval_pre(t01, t23);
        feval_post(k4a, k4b);
        v2f m01 = k2a + k3a, m23 = k2b + k3b;
        v2f s01 = (k1a + (m01 + m01)) + k4a;
        v2f s23 = (k1b + (m23 + m23)) + k4b;
        v2f i01 = d6 * s01, i23 = d6 * s23;
        // f64 state accumulate from f32 increment (anchor: f64 state chain)
        zd[0] += (double)i01.x; zd[1] += (double)i01.y;
        zd[2] += (double)i23.x; zd[3] += (double)i23.y;
        z01.x = (float)zd[0]; z01.y = (float)zd[1];
        z23.x = (float)zd[2]; z23.y = (float)zd[3];
    }
    decode(z01, z23, NT - 1);        // final output
}

extern "C" void kernel_launch(void* const* d_in, const int* in_sizes, int n_in,
                              void* d_out, int out_size, void* d_ws, size_t ws_size,
                              hipStream_t stream) {
    (void)in_sizes; (void)n_in; (void)out_size; (void)d_ws; (void)ws_size;
    node_kernel<<<GRID, BLOCK, 0, stream>>>(
        d_in[0],  // samp_trajs
        d_in[1],  // samp_ts
        d_in[2],  // epsilon
        d_in[3],  d_in[4],   // i2h
        d_in[5],  d_in[6],   // h2o
        d_in[7],  d_in[8],   // f1
        d_in[9],  d_in[10],  // f2
        d_in[11], d_in[12],  // f3
        d_in[13], d_in[14],  // d1
        d_in[15], d_in[16],  // d2
        d_out);
}